// Round 3
// baseline (629.542 us; speedup 1.0000x reference)
//
#include <hip/hip_runtime.h>
#include <hip/hip_bf16.h>
#include <cstdint>

typedef __attribute__((ext_vector_type(8))) short short8;            // 8 bf16 = 4 VGPRs
typedef __attribute__((ext_vector_type(16))) float floatx16;         // 32x32 MFMA C/D
typedef __attribute__((ext_vector_type(8))) unsigned short ushort8v; // 16B store

__device__ __forceinline__ unsigned short f32_to_bf16_rne(float f) {
  uint32_t u = __float_as_uint(f);
  u += 0x7FFFu + ((u >> 16) & 1u);   // RNE (inputs finite normals)
  return (unsigned short)(u >> 16);
}

// Fused conversion: blocks [0,nbx) convert x fp32->bf16; blocks [nbx,..) convert
// w int32->bf16 (exact: |w|<=128 has <=8 significand bits). 8 elems/thread, 16B stores.
__global__ void cvt_fused(const float4* __restrict__ x, const int4* __restrict__ w,
                          ushort8v* __restrict__ ox, ushort8v* __restrict__ ow,
                          int nx8, int nw8, int nbx) {
  if ((int)blockIdx.x < nbx) {
    int i = blockIdx.x * blockDim.x + threadIdx.x;
    if (i >= nx8) return;
    float4 a = x[i * 2], b = x[i * 2 + 1];
    ushort8v r;
    r[0] = f32_to_bf16_rne(a.x); r[1] = f32_to_bf16_rne(a.y);
    r[2] = f32_to_bf16_rne(a.z); r[3] = f32_to_bf16_rne(a.w);
    r[4] = f32_to_bf16_rne(b.x); r[5] = f32_to_bf16_rne(b.y);
    r[6] = f32_to_bf16_rne(b.z); r[7] = f32_to_bf16_rne(b.w);
    ox[i] = r;
  } else {
    int i = ((int)blockIdx.x - nbx) * blockDim.x + threadIdx.x;
    if (i >= nw8) return;
    int4 a = w[i * 2], b = w[i * 2 + 1];
    ushort8v r;
    r[0] = (unsigned short)(__float_as_uint((float)a.x) >> 16);
    r[1] = (unsigned short)(__float_as_uint((float)a.y) >> 16);
    r[2] = (unsigned short)(__float_as_uint((float)a.z) >> 16);
    r[3] = (unsigned short)(__float_as_uint((float)a.w) >> 16);
    r[4] = (unsigned short)(__float_as_uint((float)b.x) >> 16);
    r[5] = (unsigned short)(__float_as_uint((float)b.y) >> 16);
    r[6] = (unsigned short)(__float_as_uint((float)b.z) >> 16);
    r[7] = (unsigned short)(__float_as_uint((float)b.w) >> 16);
    ow[i] = r;
  }
}

__device__ __forceinline__ void async16(const void* g, void* l) {
  // global -> LDS direct copy, 16 B/lane; LDS dest is wave-uniform base + lane*16
  __builtin_amdgcn_global_load_lds((__attribute__((address_space(1))) void*)(g),
                                   (__attribute__((address_space(3))) void*)(l), 16, 0, 0);
}

// C[m,n] = scale[n] * sum_k A[m,k]*B[n,k] + bias[n]
// A: [M,K] bf16 bits, B: [N,K] bf16 bits (B^T layout), C: [M,N] fp32
// 32x32x16 MFMA (2382 TF ubench vs 2075 for 16x16x32; half the instr issues).
// LDS XOR swizzle: physical 16B seg = logical seg ^ ((row>>1)&3) -> ds_read_b128
// phases hit all 8 bank-quads (verified R2: SQ_LDS_BANK_CONFLICT = 0) while the
// global_load_lds destination stays tid-contiguous (wave-uniform-base constraint).
__global__ __launch_bounds__(256) void gemm_bt_bf16(
    const unsigned short* __restrict__ A, const unsigned short* __restrict__ B,
    const float* __restrict__ scale, const float* __restrict__ bias,
    float* __restrict__ C, int M, int N, int K) {
  constexpr int BM = 128, BN = 128, BK = 32;
  __shared__ unsigned short sA[BM * BK];  // 8 KB
  __shared__ unsigned short sB[BN * BK];  // 8 KB

  const int tid  = threadIdx.x;
  const int lane = tid & 63;
  const int wv   = tid >> 6;        // 4 waves, 2x2 grid, each owns 64x64
  const int wm   = wv >> 1;
  const int wn   = wv & 1;
  const int aM   = blockIdx.y * BM;
  const int bN   = blockIdx.x * BN;

  // --- staging: 128 rows x 4 segs(16B) = 512 lane-tasks; 2 issues/thread/matrix.
  // physical slot t holds logical (row = t>>2, seg = (t&3) ^ ((row>>1)&3))
  const int t0 = tid, t1 = tid + 256;
  const int r0 = t0 >> 2, s0 = (t0 & 3) ^ ((r0 >> 1) & 3);
  const int r1 = t1 >> 2, s1 = (t1 & 3) ^ ((r1 >> 1) & 3);
  const unsigned short* gA0 = A + (size_t)(aM + r0) * K + s0 * 8;
  const unsigned short* gA1 = A + (size_t)(aM + r1) * K + s1 * 8;
  const unsigned short* gB0 = B + (size_t)(bN + r0) * K + s0 * 8;
  const unsigned short* gB1 = B + (size_t)(bN + r1) * K + s1 * 8;
  unsigned short* lA0 = sA + t0 * 8;
  unsigned short* lA1 = sA + t1 * 8;
  unsigned short* lB0 = sB + t0 * 8;
  unsigned short* lB1 = sB + t1 * 8;

  // --- frag reads: 32x32x16 A-operand layout A[m=lane&31][k=(lane>>5)*8+j]
  // (analog of m120-verified 16x16 layout). Same XOR swizzle on the 16B seg.
  const int row32 = lane & 31;
  const int half  = lane >> 5;
  const int sw    = (row32 >> 1) & 3;
  // precompute the 4 seg offsets (elements) for khalf 0/1 after swizzle
  const int segk0 = ((0 * 2 + half) ^ sw) * 8;
  const int segk1 = ((1 * 2 + half) ^ sw) * 8;
  const unsigned short* rA = sA + (size_t)(wm * 64 + row32) * BK;
  const unsigned short* rB = sB + (size_t)(wn * 64 + row32) * BK;

  floatx16 acc[2][2] = {};

  for (int k0 = 0; k0 < K; k0 += BK) {
    __syncthreads();  // previous iter's LDS reads done before overwrite
    async16(gA0, lA0);
    async16(gA1, lA1);
    async16(gB0, lB0);
    async16(gB1, lB1);
    gA0 += BK; gA1 += BK; gB0 += BK; gB1 += BK;
    __syncthreads();  // drains vmcnt(0): staged tiles visible

    short8 af[2][2], bfr[2][2];   // [tile][khalf]
#pragma unroll
    for (int t = 0; t < 2; ++t) {
      af[t][0]  = *(const short8*)(rA + t * 32 * BK + segk0);
      af[t][1]  = *(const short8*)(rA + t * 32 * BK + segk1);
      bfr[t][0] = *(const short8*)(rB + t * 32 * BK + segk0);
      bfr[t][1] = *(const short8*)(rB + t * 32 * BK + segk1);
    }
#pragma unroll
    for (int i = 0; i < 2; ++i)
#pragma unroll
      for (int j = 0; j < 2; ++j) {
        acc[i][j] = __builtin_amdgcn_mfma_f32_32x32x16_bf16(af[i][0], bfr[j][0], acc[i][j], 0, 0, 0);
        acc[i][j] = __builtin_amdgcn_mfma_f32_32x32x16_bf16(af[i][1], bfr[j][1], acc[i][j], 0, 0, 0);
      }
  }

  // --- epilogue: 32x32 C/D layout col=lane&31, row=(reg&3)+8*(reg>>2)+4*(lane>>5)
  // (m74/m101-verified)
#pragma unroll
  for (int j = 0; j < 2; ++j) {
    const int n = bN + wn * 64 + j * 32 + row32;
    const float s = scale[n];
    const float b = bias[n];
#pragma unroll
    for (int i = 0; i < 2; ++i) {
      const int mb = aM + wm * 64 + i * 32 + half * 4;
      floatx16 c = acc[i][j];
#pragma unroll
      for (int r = 0; r < 16; ++r) {
        const int m = mb + (r & 3) + 8 * (r >> 2);
        C[(size_t)m * N + n] = c[r] * s + b;
      }
    }
  }
}

// Insurance only: used if ws_size is too small for the bf16 staging buffers.
__global__ void naive_kernel(const float* __restrict__ x, const int* __restrict__ w,
                             const float* __restrict__ s, const float* __restrict__ b,
                             float* __restrict__ y, int M, int N, int K) {
  int n = blockIdx.x * blockDim.x + threadIdx.x;
  int m = blockIdx.y;
  if (n >= N) return;
  float acc = 0.f;
  for (int k = 0; k < K; ++k) acc += x[(size_t)m * K + k] * (float)w[(size_t)n * K + k];
  y[(size_t)m * N + n] = acc * s[n] + b[n];
}

extern "C" void kernel_launch(void* const* d_in, const int* in_sizes, int n_in,
                              void* d_out, int out_size, void* d_ws, size_t ws_size,
                              hipStream_t stream) {
  const float* x     = (const float*)d_in[0];
  const int*   wq    = (const int*)d_in[1];
  const float* scale = (const float*)d_in[2];
  const float* bias  = (const float*)d_in[3];
  float* y = (float*)d_out;

  const int xN = in_sizes[0];           // M*K
  const int wN = in_sizes[1];           // N*K
  const int N  = in_sizes[2];           // D_OUT
  const int K  = wN / N;
  const int M  = xN / K;

  const size_t need = (size_t)xN * 2 + (size_t)wN * 2;  // 96 MiB here
  if (ws_size >= need && (M % 128) == 0 && (N % 128) == 0 && (K % 32) == 0 &&
      (xN % 2048) == 0 && (wN % 2048) == 0) {
    unsigned short* xb = (unsigned short*)d_ws;
    unsigned short* wb = xb + (size_t)xN;
    const int nx8 = xN / 8, nw8 = wN / 8;
    const int nbx = nx8 / 256, nbw = nw8 / 256;
    cvt_fused<<<nbx + nbw, 256, 0, stream>>>((const float4*)x, (const int4*)wq,
                                             (ushort8v*)xb, (ushort8v*)wb, nx8, nw8, nbx);
    dim3 grid(N / 128, M / 128);
    gemm_bt_bf16<<<grid, 256, 0, stream>>>(xb, wb, scale, bias, y, M, N, K);
  } else {
    dim3 grid((N + 255) / 256, M);
    naive_kernel<<<grid, 256, 0, stream>>>(x, wq, scale, bias, y, M, N, K);
  }
}

// Round 4
// 556.637 us; speedup vs baseline: 1.1310x; 1.1310x over previous
//
#include <hip/hip_runtime.h>
#include <hip/hip_bf16.h>
#include <cstdint>

typedef __attribute__((ext_vector_type(8))) short short8;            // 8 bf16 = 4 VGPRs
typedef __attribute__((ext_vector_type(4))) float floatx4;           // MFMA C/D

__device__ __forceinline__ unsigned short f32_to_bf16_rne(float f) {
  uint32_t u = __float_as_uint(f);
  u += 0x7FFFu + ((u >> 16) & 1u);   // RNE (inputs finite normals)
  return (unsigned short)(u >> 16);
}

__device__ __forceinline__ ushort4 cvt4_f(float4 v) {
  ushort4 r;
  r.x = f32_to_bf16_rne(v.x); r.y = f32_to_bf16_rne(v.y);
  r.z = f32_to_bf16_rne(v.z); r.w = f32_to_bf16_rne(v.w);
  return r;
}
__device__ __forceinline__ ushort4 cvt4_i(int4 v) {
  ushort4 r;
  r.x = (unsigned short)(__float_as_uint((float)v.x) >> 16);
  r.y = (unsigned short)(__float_as_uint((float)v.y) >> 16);
  r.z = (unsigned short)(__float_as_uint((float)v.z) >> 16);
  r.w = (unsigned short)(__float_as_uint((float)v.w) >> 16);
  return r;
}

// Fused conversion, lane-dense coalescing: loads 16 B/lane dense, stores 8 B/lane
// dense. Blocks [0,nbx) convert x fp32->bf16; rest convert w int32->bf16 (exact).
// Each block handles 512 vec4 elements (2048 scalars).
__global__ void cvt_fused(const float4* __restrict__ x, const int4* __restrict__ w,
                          ushort4* __restrict__ ox, ushort4* __restrict__ ow, int nbx) {
  const int t = threadIdx.x;
  if ((int)blockIdx.x < nbx) {
    const int base = blockIdx.x * 512;
    float4 a = x[base + t];
    float4 b = x[base + 256 + t];
    ox[base + t]       = cvt4_f(a);
    ox[base + 256 + t] = cvt4_f(b);
  } else {
    const int base = ((int)blockIdx.x - nbx) * 512;
    int4 a = w[base + t];
    int4 b = w[base + 256 + t];
    ow[base + t]       = cvt4_i(a);
    ow[base + 256 + t] = cvt4_i(b);
  }
}

__device__ __forceinline__ void async16(const void* g, void* l) {
  // global -> LDS direct copy, 16 B/lane; LDS dest is wave-uniform base + lane*16
  __builtin_amdgcn_global_load_lds((__attribute__((address_space(1))) void*)(g),
                                   (__attribute__((address_space(3))) void*)(l), 16, 0, 0);
}

// C[m,n] = scale[n] * sum_k A[m,k]*B[n,k] + bias[n]
// A: [M,K] bf16 bits, B: [N,K] bf16 bits (B^T layout), C: [M,N] fp32
// Pipelined single-buffer K-loop: frag reads -> barrier -> issue next tile's DMA
// -> MFMA (DMA flies during MFMAs; drain at next top barrier sees it ~done).
// LDS XOR swizzle (R2-verified: SQ_LDS_BANK_CONFLICT = 0).
__global__ __launch_bounds__(256) void gemm_bt_bf16(
    const unsigned short* __restrict__ A, const unsigned short* __restrict__ B,
    const float* __restrict__ scale, const float* __restrict__ bias,
    float* __restrict__ C, int M, int N, int K) {
  constexpr int BM = 128, BN = 128, BK = 32;
  __shared__ unsigned short sA[BM * BK];  // 8 KB
  __shared__ unsigned short sB[BN * BK];  // 8 KB

  const int tid  = threadIdx.x;
  const int lane = tid & 63;
  const int wv   = tid >> 6;        // 4 waves, 2x2 grid, each owns 64x64
  const int wm   = wv >> 1;
  const int wn   = wv & 1;
  const int aM   = blockIdx.y * BM;
  const int bN   = blockIdx.x * BN;

  // --- staging: 128 rows x 4 segs(16B) = 512 lane-tasks; 2 issues/thread/matrix.
  // physical slot t holds logical (row = t>>2, seg = (t&3) ^ ((row>>1)&3))
  const int t0 = tid, t1 = tid + 256;
  const int r0 = t0 >> 2, s0 = (t0 & 3) ^ ((r0 >> 1) & 3);
  const int r1 = t1 >> 2, s1 = (t1 & 3) ^ ((r1 >> 1) & 3);
  const unsigned short* gA0 = A + (size_t)(aM + r0) * K + s0 * 8;
  const unsigned short* gA1 = A + (size_t)(aM + r1) * K + s1 * 8;
  const unsigned short* gB0 = B + (size_t)(bN + r0) * K + s0 * 8;
  const unsigned short* gB1 = B + (size_t)(bN + r1) * K + s1 * 8;
  unsigned short* lA0 = sA + t0 * 8;
  unsigned short* lA1 = sA + t1 * 8;
  unsigned short* lB0 = sB + t0 * 8;
  unsigned short* lB1 = sB + t1 * 8;

  // --- LDS->frag reads (R2-verified conflict-free): A[m=lane&15][k=quad*8+j],
  // physical seg = quad ^ ((row>>1)&3)
  const int row  = lane & 15;
  const int quad = lane >> 4;
  const int sw   = (row >> 1) & 3;
  const unsigned short* rA = sA + (size_t)(wm * 64 + row) * BK + (quad ^ sw) * 8;
  const unsigned short* rB = sB + (size_t)(wn * 64 + row) * BK + (quad ^ sw) * 8;

  floatx4 acc[4][4] = {};

  // prologue: stage tile 0
  async16(gA0, lA0);
  async16(gA1, lA1);
  async16(gB0, lB0);
  async16(gB1, lB1);

  for (int k0 = 0; k0 < K; k0 += BK) {
    __syncthreads();  // drains vmcnt(0): tile k0 visible (loads issued 1 iter ago)

    short8 af[4], bf[4];
#pragma unroll
    for (int t = 0; t < 4; ++t) {
      af[t] = *(const short8*)(rA + t * 16 * BK);
      bf[t] = *(const short8*)(rB + t * 16 * BK);
    }

    __syncthreads();  // lgkm only: all waves finished reading LDS

    if (k0 + BK < K) {  // issue next tile's DMA; it overlaps the MFMAs below
      gA0 += BK; gA1 += BK; gB0 += BK; gB1 += BK;
      async16(gA0, lA0);
      async16(gA1, lA1);
      async16(gB0, lB0);
      async16(gB1, lB1);
    }

#pragma unroll
    for (int i = 0; i < 4; ++i)
#pragma unroll
      for (int j = 0; j < 4; ++j)
        acc[i][j] = __builtin_amdgcn_mfma_f32_16x16x32_bf16(af[i], bf[j], acc[i][j], 0, 0, 0);
  }

  // --- epilogue: C/D layout col=lane&15, row=(lane>>4)*4+reg (m89-verified)
#pragma unroll
  for (int j = 0; j < 4; ++j) {
    const int n = bN + wn * 64 + j * 16 + row;
    const float s = scale[n];
    const float b = bias[n];
#pragma unroll
    for (int i = 0; i < 4; ++i) {
      const int m0 = aM + wm * 64 + i * 16 + quad * 4;
      floatx4 c = acc[i][j];
      C[(size_t)(m0 + 0) * N + n] = c[0] * s + b;
      C[(size_t)(m0 + 1) * N + n] = c[1] * s + b;
      C[(size_t)(m0 + 2) * N + n] = c[2] * s + b;
      C[(size_t)(m0 + 3) * N + n] = c[3] * s + b;
    }
  }
}

// Insurance only: used if ws_size is too small for the bf16 staging buffers.
__global__ void naive_kernel(const float* __restrict__ x, const int* __restrict__ w,
                             const float* __restrict__ s, const float* __restrict__ b,
                             float* __restrict__ y, int M, int N, int K) {
  int n = blockIdx.x * blockDim.x + threadIdx.x;
  int m = blockIdx.y;
  if (n >= N) return;
  float acc = 0.f;
  for (int k = 0; k < K; ++k) acc += x[(size_t)m * K + k] * (float)w[(size_t)n * K + k];
  y[(size_t)m * N + n] = acc * s[n] + b[n];
}

extern "C" void kernel_launch(void* const* d_in, const int* in_sizes, int n_in,
                              void* d_out, int out_size, void* d_ws, size_t ws_size,
                              hipStream_t stream) {
  const float* x     = (const float*)d_in[0];
  const int*   wq    = (const int*)d_in[1];
  const float* scale = (const float*)d_in[2];
  const float* bias  = (const float*)d_in[3];
  float* y = (float*)d_out;

  const int xN = in_sizes[0];           // M*K
  const int wN = in_sizes[1];           // N*K
  const int N  = in_sizes[2];           // D_OUT
  const int K  = wN / N;
  const int M  = xN / K;

  const size_t need = (size_t)xN * 2 + (size_t)wN * 2;  // 96 MiB here
  if (ws_size >= need && (M % 128) == 0 && (N % 128) == 0 && (K % 32) == 0 &&
      (xN % 2048) == 0 && (wN % 2048) == 0) {
    unsigned short* xb = (unsigned short*)d_ws;
    unsigned short* wb = xb + (size_t)xN;
    const int nbx = xN / 2048, nbw = wN / 2048;
    cvt_fused<<<nbx + nbw, 256, 0, stream>>>((const float4*)x, (const int4*)wq,
                                             (ushort4*)xb, (ushort4*)wb, nbx);
    dim3 grid(N / 128, M / 128);
    gemm_bt_bf16<<<grid, 256, 0, stream>>>(xb, wb, scale, bias, y, M, N, K);
  } else {
    dim3 grid((N + 255) / 256, M);
    naive_kernel<<<grid, 256, 0, stream>>>(x, wq, scale, bias, y, M, N, K);
  }
}